// Round 7
// baseline (307.389 us; speedup 1.0000x reference)
//
#include <hip/hip_runtime.h>

typedef unsigned short ushort_t;
typedef _Float16 half8 __attribute__((ext_vector_type(8)));
typedef short short8 __attribute__((ext_vector_type(8)));
typedef float floatx4 __attribute__((ext_vector_type(4)));

#define NCC 65536
#define NPP 1024
#define DD 256
#define NCHUNK 64
#define VROW 40                   // padded vT row in halves (80B: 16B-aligned, b128 bank-balanced)
#define VTILE_B (256 * VROW * 2)  // 20480 B per 32-candidate vT tile
#define L2E 1.44269504f
#define CLIPL 72.134752f          // 50 * log2(e)

static __device__ __forceinline__ ushort_t f2h_bits(float x) {
  _Float16 h = (_Float16)x;
  return __builtin_bit_cast(ushort_t, h);
}
static __device__ __forceinline__ ushort_t f2bf_bits(float x) {
  unsigned u = __builtin_bit_cast(unsigned, x);
  unsigned r = (u + 0x7FFFu + ((u >> 16) & 1u)) >> 16;
  return (ushort_t)r;
}
static __device__ __forceinline__ float bf2f(ushort_t b) {
  unsigned u = ((unsigned)b) << 16;
  return __builtin_bit_cast(float, u);
}
// load 8 consecutive fp32, convert to f16 frag
static __device__ __forceinline__ half8 cvt8(const float* p) {
  float4 a = *(const float4*)p, b = *(const float4*)(p + 4);
  half8 h;
  h[0] = (_Float16)a.x; h[1] = (_Float16)a.y; h[2] = (_Float16)a.z; h[3] = (_Float16)a.w;
  h[4] = (_Float16)b.x; h[5] = (_Float16)b.y; h[6] = (_Float16)b.z; h[7] = (_Float16)b.w;
  return h;
}
// async global->LDS DMA, 16B per lane
static __device__ __forceinline__ void dma16(const void* g, void* l) {
  __builtin_amdgcn_global_load_lds((const __attribute__((address_space(1))) unsigned int*)g,
                                   (__attribute__((address_space(3))) unsigned int*)l, 16, 0, 0);
}

// ---------------------------------------------------------------------------
// K_A1: MkF = Wk @ Wq^T stored in MFMA B-frag order so gt loads are coalesced:
// element (mr, e) -> slot ((mr>>4)*8 + (e>>5))*64 + ((e>>3)&3)*16 + (mr&15),
// half index e&7. Block 16: tu = Wk@bq, tv = Wq@bk, s0 = bk.bq
// ---------------------------------------------------------------------------
__global__ __launch_bounds__(256) void mk_prep(const float* __restrict__ Wq,
                                               const float* __restrict__ Wk,
                                               const float* __restrict__ bq,
                                               const float* __restrict__ bk,
                                               ushort_t* __restrict__ MkF, float* __restrict__ tu,
                                               float* __restrict__ tv, float* __restrict__ s0v) {
  const int t = threadIdx.x;
  if (blockIdx.x == 16) {
    float su = 0.f, sv = 0.f;
    for (int j = 0; j < DD; j += 4) {
      float4 a = *(const float4*)&Wk[(size_t)t * DD + j];
      float4 b = *(const float4*)&bq[j];
      su += a.x * b.x + a.y * b.y + a.z * b.z + a.w * b.w;
      float4 c = *(const float4*)&Wq[(size_t)t * DD + j];
      float4 d = *(const float4*)&bk[j];
      sv += c.x * d.x + c.y * d.y + c.z * d.z + c.w * d.w;
    }
    tu[t] = su;
    tv[t] = sv;
    __shared__ float red[256];
    red[t] = bk[t] * bq[t];
    __syncthreads();
    for (int o = 128; o; o >>= 1) {
      if (t < o) red[t] += red[t + o];
      __syncthreads();
    }
    if (t == 0) s0v[0] = red[0];
    return;
  }
  const int m0 = ((int)blockIdx.x & 3) * 64, e0 = ((int)blockIdx.x >> 2) * 64;
  const int w = t >> 6, lane = t & 63, qd = lane >> 4, n = lane & 15;
  floatx4 acc[4] = {};
#pragma unroll
  for (int s = 0; s < 8; s++) {
    half8 af = cvt8(&Wk[(size_t)(m0 + w * 16 + n) * DD + s * 32 + qd * 8]);
#pragma unroll
    for (int nt = 0; nt < 4; ++nt) {
      half8 bf = cvt8(&Wq[(size_t)(e0 + nt * 16 + n) * DD + s * 32 + qd * 8]);
      acc[nt] = __builtin_amdgcn_mfma_f32_16x16x32_f16(af, bf, acc[nt], 0, 0, 0);
    }
  }
#pragma unroll
  for (int nt = 0; nt < 4; ++nt)
#pragma unroll
    for (int r = 0; r < 4; r++) {
      int mr = m0 + w * 16 + qd * 4 + r;
      int e = e0 + nt * 16 + n;
      size_t slot = ((size_t)(mr >> 4) * 8 + (e >> 5)) * 64 + ((e >> 3) & 3) * 16 + (mr & 15);
      MkF[slot * 8 + (e & 7)] = f2h_bits(acc[nt][r]);
    }
}

// ---------------------------------------------------------------------------
// K_B (fused): blocks 0..2047 = bt work (box_feat single pass); blocks
// 2048..2063 = gt work (Gt = pf @ Mk^T from frag-ordered MkF + gamma).
// bt outputs:
//  - bfR: f16 rows, 16B-group XOR swizzle with key (c&3)|((c>>1)&4) so the
//    sigma-permuted QK A-frag reads (reader xor = n&7) are bank-balanced
//  - vTb: bf16 transposed tiles [tile][d][VROW=40]
//  - meta[c] = (alpha, beta, xs, ys)
// ---------------------------------------------------------------------------
__global__ __launch_bounds__(256) void btgt_prep(
    const float* __restrict__ bf, const float* __restrict__ pf,
    const float* __restrict__ centers, const float* __restrict__ scales,
    const float* __restrict__ tu, const float* __restrict__ tv,
    const float* __restrict__ s0v, const ushort_t* __restrict__ MkF,
    ushort_t* __restrict__ bfR, ushort_t* __restrict__ vTb, float4* __restrict__ meta,
    ushort_t* __restrict__ Gt, float* __restrict__ gamma) {
  const int t = threadIdx.x;
  if (blockIdx.x >= (NCC / 32)) {
    // ---- gt path ----
    const int p0 = ((int)blockIdx.x - NCC / 32) * 64;
    const int w = t >> 6, lane = t & 63, qd = lane >> 4, n = lane & 15;
    floatx4 acc[16] = {};
#pragma unroll
    for (int s = 0; s < 8; s++) {
      half8 af = cvt8(&pf[(size_t)(p0 + w * 16 + n) * DD + s * 32 + qd * 8]);
#pragma unroll
      for (int nt = 0; nt < 16; ++nt) {
        half8 bfr = __builtin_bit_cast(
            half8, *(const uint4*)&MkF[(((size_t)nt * 8 + s) * 64 + lane) * 8]);
        acc[nt] = __builtin_amdgcn_mfma_f32_16x16x32_f16(af, bfr, acc[nt], 0, 0, 0);
      }
    }
#pragma unroll
    for (int nt = 0; nt < 16; ++nt)
#pragma unroll
      for (int r = 0; r < 4; r++)
        Gt[(size_t)(p0 + w * 16 + qd * 4 + r) * DD + nt * 16 + n] = f2h_bits(acc[nt][r]);
    if (t < 64) {
      float s = s0v[0];
      for (int j = 0; j < DD; j += 4) {
        float4 a = *(const float4*)&pf[(size_t)(p0 + t) * DD + j];
        float4 b = *(const float4*)&tv[j];
        s += a.x * b.x + a.y * b.y + a.z * b.z + a.w * b.w;
      }
      gamma[p0 + t] = s * L2E - CLIPL;
    }
    return;
  }
  // ---- bt path ----
  __shared__ float tu_s[256];
  __shared__ __align__(16) ushort_t lt[256][VROW];
  const int c0 = (int)blockIdx.x * 32;
  tu_s[t] = tu[t];
  __syncthreads();
  const int c = t >> 3, sub = t & 7;
  const int kc = ((c0 + c) & 3) | (((c0 + c) >> 1) & 4);
  float du = 0.f;
#pragma unroll
  for (int i = 0; i < 8; i++) {
    int f4 = sub + 8 * i;
    int d0 = f4 * 4;
    float4 v = *(const float4*)&bf[(size_t)(c0 + c) * DD + d0];
    du += v.x * tu_s[d0] + v.y * tu_s[d0 + 1] + v.z * tu_s[d0 + 2] + v.w * tu_s[d0 + 3];
    // f16 row-major with XOR swizzle (16B groups), key kc
    int l = f4 >> 1;
    int u = (l & ~7) | ((l & 7) ^ kc);
    ushort_t h0 = f2h_bits(v.x), h1 = f2h_bits(v.y), h2 = f2h_bits(v.z), h3 = f2h_bits(v.w);
    *(uint2*)&bfR[(size_t)(c0 + c) * DD + u * 8 + (d0 & 7)] =
        make_uint2((unsigned)h0 | ((unsigned)h1 << 16), (unsigned)h2 | ((unsigned)h3 << 16));
    // transposed bf16 staging
    lt[d0 + 0][c] = f2bf_bits(v.x);
    lt[d0 + 1][c] = f2bf_bits(v.y);
    lt[d0 + 2][c] = f2bf_bits(v.z);
    lt[d0 + 3][c] = f2bf_bits(v.w);
  }
  du += __shfl_xor(du, 1, 64);
  du += __shfl_xor(du, 2, 64);
  du += __shfl_xor(du, 4, 64);
  if (sub == 0) {
    const float4 ce = *(const float4*)&centers[(size_t)(c0 + c) * 4];  // y,x,stride,stride
    int lvl = (int)(log2f(ce.w) + 0.5f) - 3;
    lvl = lvl < 0 ? 0 : (lvl > 4 ? 4 : lvl);
    float wsc = scales[lvl];
    float hf = floorf(ce.z * 0.5f);
    meta[c0 + c] = make_float4(wsc * L2E, wsc * du * L2E, ce.y + hf, ce.x + hf);
  }
  __syncthreads();
  // copyout vT tile: thread t = row d, 80B = 5 x uint4
  char* dst = (char*)vTb + (size_t)blockIdx.x * VTILE_B + (size_t)t * (VROW * 2);
  const char* src = (const char*)&lt[t][0];
#pragma unroll
  for (int i = 0; i < 5; i++) *(uint4*)(dst + i * 16) = *(const uint4*)(src + i * 16);
}

// ---------------------------------------------------------------------------
// K3: fused attention, register-identity P. Block = 4 waves x 32 points;
// grid (64 chunks, 8 pg). QK loads candidate rows PERMUTED:
// acc_t row m loads candidate sigma_t(m) = 8*(m>>2) + 4t + (m&3), so lane
// (qd,n)'s 8 sim regs are exactly c = qd*8 + 4t + r == the 16x16x32 bf16
// A-fragment for PV. No P LDS round-trip, no lgkmcnt drain. One barrier/iter;
// kf+vT DMA double-buffered (staged right after barrier, drains at next).
// ---------------------------------------------------------------------------
template <bool PART>
__global__ __launch_bounds__(256, 2) void attn_kernel(
    const ushort_t* __restrict__ Gt, const float* __restrict__ gamma,
    const ushort_t* __restrict__ bfR, const ushort_t* __restrict__ vTb,
    const float4* __restrict__ meta, const float* __restrict__ boxes,
    void* __restrict__ acc_out, float* __restrict__ den_out) {
  __shared__ __align__(16) ushort_t lds_k[2][32 * 256];    // 32KB
  __shared__ __align__(16) ushort_t lds_v[2][256 * VROW];  // 40KB

  const int t = threadIdx.x;
  const int w = t >> 6, lane = t & 63, qd = lane >> 4, n = lane & 15;
  const int chunk = blockIdx.x;
  const int p0w = blockIdx.y * 128 + w * 32;
  const int cchunk = chunk * 1024;
  const int sw16 = (n & 7) * 16;

  half8 gfr[2][8];
  float4 bxv[2];
  float gam[2];
#pragma unroll
  for (int pt = 0; pt < 2; ++pt) {
    int p = p0w + pt * 16 + n;
#pragma unroll
    for (int s = 0; s < 8; s++)
      gfr[pt][s] = __builtin_bit_cast(half8, *(const uint4*)&Gt[(size_t)p * DD + s * 32 + qd * 8]);
    bxv[pt] = *(const float4*)&boxes[(size_t)p * 4];
    gam[pt] = gamma[p];
  }

  floatx4 macc[2][16] = {};
  float dsum0 = 0.f, dsum1 = 0.f;

  auto stage = [&](int it2, int b) {
    const char* ks = (const char*)bfR + (size_t)(cchunk + it2 * 32) * 512;
    char* kd = (char*)lds_k[b];
#pragma unroll
    for (int j = 0; j < 4; ++j) {
      int i = w * 4 + j;
      dma16(ks + i * 1024 + lane * 16, kd + i * 1024 + lane * 16);
    }
    const char* vs = (const char*)vTb + ((size_t)(cchunk >> 5) + it2) * VTILE_B;
    char* vd = (char*)lds_v[b];
#pragma unroll
    for (int j = 0; j < 5; ++j) {
      int i = w * 5 + j;
      dma16(vs + i * 1024 + lane * 16, vd + i * 1024 + lane * 16);
    }
  };

  stage(0, 0);

  for (int it = 0; it < 32; ++it) {
    const int buf = it & 1;
    const int cb = cchunk + it * 32;
    __syncthreads();                          // drains stage(it)
    if (it + 1 < 32) stage(it + 1, buf ^ 1);  // drains at NEXT barrier

    // QK^T with sigma-permuted candidate rows; 4 independent MFMA chains
    floatx4 at[2][2] = {};
#pragma unroll
    for (int t2 = 0; t2 < 2; ++t2) {
      const char* krow =
          (const char*)lds_k[buf] + ((((n & 12) << 1) + (n & 3) + 4 * t2) * 512);
#pragma unroll
      for (int s = 0; s < 8; s++) {
        half8 af = __builtin_bit_cast(half8, *(const uint4*)(krow + ((s * 64 + qd * 16) ^ sw16)));
        at[t2][0] = __builtin_amdgcn_mfma_f32_16x16x32_f16(af, gfr[0][s], at[t2][0], 0, 0, 0);
        at[t2][1] = __builtin_amdgcn_mfma_f32_16x16x32_f16(af, gfr[1][s], at[t2][1], 0, 0, 0);
      }
    }
    // mask/exp; pack directly into PV A-frag registers (c = qd*8 + 4*t2 + r)
    unsigned pk0[4], pk1[4];
#pragma unroll
    for (int t2 = 0; t2 < 2; ++t2) {
#pragma unroll
      for (int r = 0; r < 4; r++) {
        float4 mt = meta[cb + 8 * qd + 4 * t2 + r];  // alpha, beta, xs, ys
        {
          float mn = fminf(fminf(mt.z - bxv[0].x, mt.w - bxv[0].y),
                           fminf(bxv[0].z - mt.z, bxv[0].w - mt.w));
          float targ = fmaf(mt.x, at[t2][0][r], mt.y) + gam[0];
          float e = (mn > 0.f) ? exp2f(fminf(targ, 0.f)) : 0.f;
          dsum0 += e;
          unsigned b = (unsigned)f2bf_bits(e);
          unsigned idx = t2 * 2 + (r >> 1);
          if ((r & 1) == 0) pk0[idx] = b;
          else pk0[idx] |= b << 16;
        }
        {
          float mn = fminf(fminf(mt.z - bxv[1].x, mt.w - bxv[1].y),
                           fminf(bxv[1].z - mt.z, bxv[1].w - mt.w));
          float targ = fmaf(mt.x, at[t2][1][r], mt.y) + gam[1];
          float e = (mn > 0.f) ? exp2f(fminf(targ, 0.f)) : 0.f;
          dsum1 += e;
          unsigned b = (unsigned)f2bf_bits(e);
          unsigned idx = t2 * 2 + (r >> 1);
          if ((r & 1) == 0) pk1[idx] = b;
          else pk1[idx] |= b << 16;
        }
      }
    }
    uint4 u0, u1;
    u0.x = pk0[0]; u0.y = pk0[1]; u0.z = pk0[2]; u0.w = pk0[3];
    u1.x = pk1[0]; u1.y = pk1[1]; u1.z = pk1[2]; u1.w = pk1[3];
    short8 a20 = __builtin_bit_cast(short8, u0);
    short8 a21 = __builtin_bit_cast(short8, u1);
#pragma unroll
    for (int dt = 0; dt < 16; ++dt) {
      short8 b2 = __builtin_bit_cast(
          short8, *(const uint4*)&lds_v[buf][(dt * 16 + n) * VROW + qd * 8]);
      macc[0][dt] = __builtin_amdgcn_mfma_f32_16x16x32_bf16(a20, b2, macc[0][dt], 0, 0, 0);
      macc[1][dt] = __builtin_amdgcn_mfma_f32_16x16x32_bf16(a21, b2, macc[1][dt], 0, 0, 0);
    }
  }

  dsum0 += __shfl_xor(dsum0, 16, 64);
  dsum0 += __shfl_xor(dsum0, 32, 64);
  dsum1 += __shfl_xor(dsum1, 16, 64);
  dsum1 += __shfl_xor(dsum1, 32, 64);

  if (PART) {
    if (lane < 16) {
      den_out[(size_t)chunk * NPP + p0w + n] = dsum0;
      den_out[(size_t)chunk * NPP + p0w + 16 + n] = dsum1;
    }
    ushort_t* ab = (ushort_t*)acc_out + (size_t)chunk * NPP * DD;
#pragma unroll
    for (int pt = 0; pt < 2; ++pt)
#pragma unroll
      for (int dt = 0; dt < 16; ++dt)
#pragma unroll
        for (int r = 0; r < 4; r++)
          ab[(size_t)(p0w + pt * 16 + qd * 4 + r) * DD + dt * 16 + n] = f2bf_bits(macc[pt][dt][r]);
  } else {
    if (lane < 16) {
      atomicAdd(&den_out[p0w + n], dsum0);
      atomicAdd(&den_out[p0w + 16 + n], dsum1);
    }
    float* ab = (float*)acc_out;
#pragma unroll
    for (int pt = 0; pt < 2; ++pt)
#pragma unroll
      for (int dt = 0; dt < 16; ++dt)
#pragma unroll
        for (int r = 0; r < 4; r++)
          atomicAdd(&ab[(size_t)(p0w + pt * 16 + qd * 4 + r) * DD + dt * 16 + n],
                    macc[pt][dt][r]);
  }
}

// ---------------------------------------------------------------------------
// K4a: reduce bf16 partials over chunks + finalize (PART path)
// ---------------------------------------------------------------------------
__global__ __launch_bounds__(256) void reduce_finalize(const float* __restrict__ points_feat,
                                                       const ushort_t* __restrict__ acc_part,
                                                       const float* __restrict__ den_part,
                                                       float* __restrict__ out) {
  const int p = blockIdx.x, t = threadIdx.x;
  float s = 0.f;
#pragma unroll 4
  for (int c = 0; c < NCHUNK; ++c) s += bf2f(acc_part[((size_t)c * NPP + p) * DD + t]);
  float dn = den_part[(size_t)(t & 63) * NPP + p];
#pragma unroll
  for (int o = 1; o < 64; o <<= 1) dn += __shfl_xor(dn, o, 64);
  float m = (dn > 0.f) ? s / dn : 0.f;
  out[(size_t)p * DD + t] = points_feat[(size_t)p * DD + t] + m;
}

// K4b: atomic-path finalize
__global__ void finalize(const float* __restrict__ points_feat, const float* __restrict__ acc,
                         const float* __restrict__ den, float* __restrict__ out) {
  int p = blockIdx.x, d = threadIdx.x;
  float dn = den[p];
  float m = (dn > 0.f) ? acc[p * DD + d] / dn : 0.f;
  out[p * DD + d] = points_feat[p * DD + d] + m;
}

extern "C" void kernel_launch(void* const* d_in, const int* in_sizes, int n_in, void* d_out,
                              int out_size, void* d_ws, size_t ws_size, hipStream_t stream) {
  const float* points_feat = (const float*)d_in[0];
  const float* box_feat = (const float*)d_in[1];
  const float* centers = (const float*)d_in[2];
  const float* boxes = (const float*)d_in[3];
  const float* Wq = (const float*)d_in[4];
  const float* bq = (const float*)d_in[5];
  const float* Wk = (const float*)d_in[6];
  const float* bk = (const float*)d_in[7];
  const float* scales = (const float*)d_in[8];

  char* p = (char*)d_ws;
  ushort_t* ws_accP = (ushort_t*)p;  p += (size_t)NCHUNK * NPP * DD * 2;  // 33.55MB (bf16)
  float* ws_den = (float*)p;         p += (size_t)NCHUNK * NPP * 4;       // 0.26MB
  ushort_t* ws_bfR = (ushort_t*)p;   p += (size_t)NCC * DD * 2;           // 33.55MB
  ushort_t* ws_vTb = (ushort_t*)p;   p += (size_t)(NCC / 32) * VTILE_B;   // 41.94MB
  ushort_t* ws_Gt = (ushort_t*)p;    p += (size_t)NPP * DD * 2;           // 0.52MB
  float4* ws_meta = (float4*)p;      p += (size_t)NCC * 16;               // 1.05MB
  float* ws_gamma = (float*)p;       p += (size_t)NPP * 4;                // 4KB
  size_t need_part = (size_t)(p - (char*)d_ws);

  if (ws_size >= need_part) {
    // aux buffers (dead once attn starts) carved from the partials region
    ushort_t* ws_Mk = ws_accP;                         // 128KB
    float* ws_tu = (float*)(ws_Mk + (size_t)DD * DD);  // 1KB
    float* ws_tv = ws_tu + DD;                         // 1KB
    float* ws_s0 = ws_tv + DD;                         // 4B

    mk_prep<<<17, 256, 0, stream>>>(Wq, Wk, bq, bk, ws_Mk, ws_tu, ws_tv, ws_s0);
    btgt_prep<<<NCC / 32 + 16, 256, 0, stream>>>(box_feat, points_feat, centers, scales, ws_tu,
                                                 ws_tv, ws_s0, ws_Mk, ws_bfR, ws_vTb, ws_meta,
                                                 ws_Gt, ws_gamma);
    attn_kernel<true><<<dim3(NCHUNK, 8), 256, 0, stream>>>(ws_Gt, ws_gamma, ws_bfR, ws_vTb,
                                                           ws_meta, boxes, ws_accP, ws_den);
    reduce_finalize<<<NPP, 256, 0, stream>>>(points_feat, ws_accP, ws_den, (float*)d_out);
  } else {
    // compact fallback: fp32 atomic accumulation
    char* q = (char*)d_ws;
    ushort_t* f_bfR = (ushort_t*)q;  q += (size_t)NCC * DD * 2;
    ushort_t* f_vTb = (ushort_t*)q;  q += (size_t)(NCC / 32) * VTILE_B;
    ushort_t* f_Gt = (ushort_t*)q;   q += (size_t)NPP * DD * 2;
    float4* f_meta = (float4*)q;     q += (size_t)NCC * 16;
    float* f_gamma = (float*)q;      q += (size_t)NPP * 4;
    float* f_den = (float*)q;        q += (size_t)NPP * 4;
    float* f_acc = (float*)q;        q += (size_t)NPP * DD * 4;
    ushort_t* f_Mk = (ushort_t*)f_acc;  // carved: consumed before memset/attn
    float* f_tu = (float*)(f_Mk + (size_t)DD * DD);
    float* f_tv = f_tu + DD;
    float* f_s0 = f_tv + DD;

    mk_prep<<<17, 256, 0, stream>>>(Wq, Wk, bq, bk, f_Mk, f_tu, f_tv, f_s0);
    btgt_prep<<<NCC / 32 + 16, 256, 0, stream>>>(box_feat, points_feat, centers, scales, f_tu,
                                                 f_tv, f_s0, f_Mk, f_bfR, f_vTb, f_meta, f_Gt,
                                                 f_gamma);
    hipMemsetAsync(f_den, 0, ((size_t)NPP * DD + NPP) * sizeof(float), stream);
    attn_kernel<false><<<dim3(NCHUNK, 8), 256, 0, stream>>>(f_Gt, f_gamma, f_bfR, f_vTb, f_meta,
                                                            boxes, f_acc, f_den);
    finalize<<<NPP, DD, 0, stream>>>(points_feat, f_acc, f_den, (float*)d_out);
  }
}

// Round 8
// 296.847 us; speedup vs baseline: 1.0355x; 1.0355x over previous
//
#include <hip/hip_runtime.h>

typedef unsigned short ushort_t;
typedef _Float16 half8 __attribute__((ext_vector_type(8)));
typedef short short8 __attribute__((ext_vector_type(8)));
typedef float floatx4 __attribute__((ext_vector_type(4)));

#define NCC 65536
#define NPP 1024
#define DD 256
#define NCHUNK 64
#define VROW 36                   // padded vT row in halves (72B: b64-pair reads conflict-free)
#define VTILE_B (256 * VROW * 2)  // 18432 B per 32-candidate vT tile
#define L2E 1.44269504f
#define CLIPL 72.134752f          // 50 * log2(e)

static __device__ __forceinline__ ushort_t f2h_bits(float x) {
  _Float16 h = (_Float16)x;
  return __builtin_bit_cast(ushort_t, h);
}
static __device__ __forceinline__ ushort_t f2bf_bits(float x) {
  unsigned u = __builtin_bit_cast(unsigned, x);
  unsigned r = (u + 0x7FFFu + ((u >> 16) & 1u)) >> 16;
  return (ushort_t)r;
}
static __device__ __forceinline__ float bf2f(ushort_t b) {
  unsigned u = ((unsigned)b) << 16;
  return __builtin_bit_cast(float, u);
}
// load 8 consecutive fp32, convert to f16 frag
static __device__ __forceinline__ half8 cvt8(const float* p) {
  float4 a = *(const float4*)p, b = *(const float4*)(p + 4);
  half8 h;
  h[0] = (_Float16)a.x; h[1] = (_Float16)a.y; h[2] = (_Float16)a.z; h[3] = (_Float16)a.w;
  h[4] = (_Float16)b.x; h[5] = (_Float16)b.y; h[6] = (_Float16)b.z; h[7] = (_Float16)b.w;
  return h;
}
// async global->LDS DMA, 16B per lane
static __device__ __forceinline__ void dma16(const void* g, void* l) {
  __builtin_amdgcn_global_load_lds((const __attribute__((address_space(1))) unsigned int*)g,
                                   (__attribute__((address_space(3))) unsigned int*)l, 16, 0, 0);
}
static __device__ __forceinline__ short8 mk_s8(uint2 lo, uint2 hi) {
  uint4 u;
  u.x = lo.x; u.y = lo.y; u.z = hi.x; u.w = hi.y;
  return __builtin_bit_cast(short8, u);
}

// ---------------------------------------------------------------------------
// K_A1: MkF = Wk @ Wq^T stored in MFMA B-frag order so gt loads are coalesced.
// Block 16: tu = Wk@bq, tv = Wq@bk, s0 = bk.bq
// ---------------------------------------------------------------------------
__global__ __launch_bounds__(256) void mk_prep(const float* __restrict__ Wq,
                                               const float* __restrict__ Wk,
                                               const float* __restrict__ bq,
                                               const float* __restrict__ bk,
                                               ushort_t* __restrict__ MkF, float* __restrict__ tu,
                                               float* __restrict__ tv, float* __restrict__ s0v) {
  const int t = threadIdx.x;
  if (blockIdx.x == 16) {
    float su = 0.f, sv = 0.f;
    for (int j = 0; j < DD; j += 4) {
      float4 a = *(const float4*)&Wk[(size_t)t * DD + j];
      float4 b = *(const float4*)&bq[j];
      su += a.x * b.x + a.y * b.y + a.z * b.z + a.w * b.w;
      float4 c = *(const float4*)&Wq[(size_t)t * DD + j];
      float4 d = *(const float4*)&bk[j];
      sv += c.x * d.x + c.y * d.y + c.z * d.z + c.w * d.w;
    }
    tu[t] = su;
    tv[t] = sv;
    __shared__ float red[256];
    red[t] = bk[t] * bq[t];
    __syncthreads();
    for (int o = 128; o; o >>= 1) {
      if (t < o) red[t] += red[t + o];
      __syncthreads();
    }
    if (t == 0) s0v[0] = red[0];
    return;
  }
  const int m0 = ((int)blockIdx.x & 3) * 64, e0 = ((int)blockIdx.x >> 2) * 64;
  const int w = t >> 6, lane = t & 63, qd = lane >> 4, n = lane & 15;
  floatx4 acc[4] = {};
#pragma unroll
  for (int s = 0; s < 8; s++) {
    half8 af = cvt8(&Wk[(size_t)(m0 + w * 16 + n) * DD + s * 32 + qd * 8]);
#pragma unroll
    for (int nt = 0; nt < 4; ++nt) {
      half8 bf = cvt8(&Wq[(size_t)(e0 + nt * 16 + n) * DD + s * 32 + qd * 8]);
      acc[nt] = __builtin_amdgcn_mfma_f32_16x16x32_f16(af, bf, acc[nt], 0, 0, 0);
    }
  }
#pragma unroll
  for (int nt = 0; nt < 4; ++nt)
#pragma unroll
    for (int r = 0; r < 4; r++) {
      int mr = m0 + w * 16 + qd * 4 + r;
      int e = e0 + nt * 16 + n;
      size_t slot = ((size_t)(mr >> 4) * 8 + (e >> 5)) * 64 + ((e >> 3) & 3) * 16 + (mr & 15);
      MkF[slot * 8 + (e & 7)] = f2h_bits(acc[nt][r]);
    }
}

// ---------------------------------------------------------------------------
// K_B (fused): blocks 0..2047 = bt (box_feat single pass); 2048..2063 = gt.
// bt outputs:
//  - bfR: f16 rows, 16B-group XOR swizzle key (c&3)|((c>>1)&4) — matches the
//    sigma-permuted QK reader key (n&7); written via LDS-staged COALESCED
//    16B stores (was 8B scattered)
//  - vTb: bf16 transposed tiles [tile][d][VROW=36]
//  - meta[c] = (alpha, beta, xs, ys)
// ---------------------------------------------------------------------------
__global__ __launch_bounds__(256) void btgt_prep(
    const float* __restrict__ bf, const float* __restrict__ pf,
    const float* __restrict__ centers, const float* __restrict__ scales,
    const float* __restrict__ tu, const float* __restrict__ tv,
    const float* __restrict__ s0v, const ushort_t* __restrict__ MkF,
    ushort_t* __restrict__ bfR, ushort_t* __restrict__ vTb, float4* __restrict__ meta,
    ushort_t* __restrict__ Gt, float* __restrict__ gamma) {
  const int t = threadIdx.x;
  if (blockIdx.x >= (NCC / 32)) {
    // ---- gt path ----
    const int p0 = ((int)blockIdx.x - NCC / 32) * 64;
    const int w = t >> 6, lane = t & 63, qd = lane >> 4, n = lane & 15;
    floatx4 acc[16] = {};
#pragma unroll
    for (int s = 0; s < 8; s++) {
      half8 af = cvt8(&pf[(size_t)(p0 + w * 16 + n) * DD + s * 32 + qd * 8]);
#pragma unroll
      for (int nt = 0; nt < 16; ++nt) {
        half8 bfr = __builtin_bit_cast(
            half8, *(const uint4*)&MkF[(((size_t)nt * 8 + s) * 64 + lane) * 8]);
        acc[nt] = __builtin_amdgcn_mfma_f32_16x16x32_f16(af, bfr, acc[nt], 0, 0, 0);
      }
    }
#pragma unroll
    for (int nt = 0; nt < 16; ++nt)
#pragma unroll
      for (int r = 0; r < 4; r++)
        Gt[(size_t)(p0 + w * 16 + qd * 4 + r) * DD + nt * 16 + n] = f2h_bits(acc[nt][r]);
    if (t < 64) {
      float s = s0v[0];
      for (int j = 0; j < DD; j += 4) {
        float4 a = *(const float4*)&pf[(size_t)(p0 + t) * DD + j];
        float4 b = *(const float4*)&tv[j];
        s += a.x * b.x + a.y * b.y + a.z * b.z + a.w * b.w;
      }
      gamma[p0 + t] = s * L2E - CLIPL;
    }
    return;
  }
  // ---- bt path ----
  __shared__ float tu_s[256];
  __shared__ __align__(16) ushort_t lt[256][VROW];
  __shared__ __align__(16) ushort_t lds_r[32][256];
  const int c0 = (int)blockIdx.x * 32;
  tu_s[t] = tu[t];
  __syncthreads();
  const int c = t >> 3, sub = t & 7;
  const int kc = ((c0 + c) & 3) | (((c0 + c) >> 1) & 4);
  float du = 0.f;
#pragma unroll
  for (int i = 0; i < 8; i++) {
    int f4 = sub + 8 * i;
    int d0 = f4 * 4;
    float4 v = *(const float4*)&bf[(size_t)(c0 + c) * DD + d0];
    du += v.x * tu_s[d0] + v.y * tu_s[d0 + 1] + v.z * tu_s[d0 + 2] + v.w * tu_s[d0 + 3];
    // f16 row with XOR swizzle (16B groups), staged to LDS
    int l = f4 >> 1;
    int u = (l & ~7) | ((l & 7) ^ kc);
    ushort_t h0 = f2h_bits(v.x), h1 = f2h_bits(v.y), h2 = f2h_bits(v.z), h3 = f2h_bits(v.w);
    *(uint2*)&lds_r[c][u * 8 + (d0 & 7)] =
        make_uint2((unsigned)h0 | ((unsigned)h1 << 16), (unsigned)h2 | ((unsigned)h3 << 16));
    // transposed bf16 staging
    lt[d0 + 0][c] = f2bf_bits(v.x);
    lt[d0 + 1][c] = f2bf_bits(v.y);
    lt[d0 + 2][c] = f2bf_bits(v.z);
    lt[d0 + 3][c] = f2bf_bits(v.w);
  }
  du += __shfl_xor(du, 1, 64);
  du += __shfl_xor(du, 2, 64);
  du += __shfl_xor(du, 4, 64);
  if (sub == 0) {
    const float4 ce = *(const float4*)&centers[(size_t)(c0 + c) * 4];  // y,x,stride,stride
    int lvl = (int)(log2f(ce.w) + 0.5f) - 3;
    lvl = lvl < 0 ? 0 : (lvl > 4 ? 4 : lvl);
    float wsc = scales[lvl];
    float hf = floorf(ce.z * 0.5f);
    meta[c0 + c] = make_float4(wsc * L2E, wsc * du * L2E, ce.y + hf, ce.x + hf);
  }
  __syncthreads();
  // coalesced bfR copyout: thread t -> row t>>3, 64B chunk t&7
  {
    int row = t >> 3, ch = t & 7;
    const uint4* src = (const uint4*)&lds_r[row][ch * 32];
    uint4* dst = (uint4*)&bfR[(size_t)(c0 + row) * DD + ch * 32];
#pragma unroll
    for (int i = 0; i < 4; i++) dst[i] = src[i];
  }
  // copyout vT tile: thread t = row d, 72B = 9 x uint2
  char* dst = (char*)vTb + (size_t)blockIdx.x * VTILE_B + (size_t)t * (VROW * 2);
  const char* src = (const char*)&lt[t][0];
#pragma unroll
  for (int i = 0; i < 9; i++) *(uint2*)(dst + i * 8) = *(const uint2*)(src + i * 8);
}

// ---------------------------------------------------------------------------
// K3: fused attention, register-identity P + meta via LDS DMA.
// Block = 4 waves x 32 points; grid (64 chunks, 8 pg). QK loads candidate
// rows PERMUTED: acc_t row m loads candidate sigma_t(m)=8*(m>>2)+4t+(m&3),
// so lane (qd,n)'s 8 sim regs are exactly c = qd*8+4t+r == the 16x16x32 bf16
// A-fragment for PV. No P LDS round-trip, no mid-iter lgkmcnt drain. One
// barrier/iter; kf+vT+meta DMA double-buffered (staged right after barrier,
// drains at next). PV B reads: b64 pairs on VROW=36 rows (conflict-free).
// ---------------------------------------------------------------------------
template <bool PART>
__global__ __launch_bounds__(256, 2) void attn_kernel(
    const ushort_t* __restrict__ Gt, const float* __restrict__ gamma,
    const ushort_t* __restrict__ bfR, const ushort_t* __restrict__ vTb,
    const float4* __restrict__ meta, const float* __restrict__ boxes,
    void* __restrict__ acc_out, float* __restrict__ den_out) {
  __shared__ __align__(16) ushort_t lds_k[2][32 * 256];    // 32KB
  __shared__ __align__(16) ushort_t lds_v[2][256 * VROW];  // 36KB
  __shared__ __align__(16) float4 lds_m[2][32];            // 1KB

  const int t = threadIdx.x;
  const int w = t >> 6, lane = t & 63, qd = lane >> 4, n = lane & 15;
  const int chunk = blockIdx.x;
  const int p0w = blockIdx.y * 128 + w * 32;
  const int cchunk = chunk * 1024;
  const int sw16 = (n & 7) * 16;

  half8 gfr[2][8];
  float4 bxv[2];
  float gam[2];
#pragma unroll
  for (int pt = 0; pt < 2; ++pt) {
    int p = p0w + pt * 16 + n;
#pragma unroll
    for (int s = 0; s < 8; s++)
      gfr[pt][s] = __builtin_bit_cast(half8, *(const uint4*)&Gt[(size_t)p * DD + s * 32 + qd * 8]);
    bxv[pt] = *(const float4*)&boxes[(size_t)p * 4];
    gam[pt] = gamma[p];
  }

  floatx4 macc[2][16] = {};
  float dsum0 = 0.f, dsum1 = 0.f;

  auto stage = [&](int it2, int b) {
    const char* ks = (const char*)bfR + (size_t)(cchunk + it2 * 32) * 512;
    char* kd = (char*)lds_k[b];
#pragma unroll
    for (int j = 0; j < 4; ++j) {
      int i = w * 4 + j;
      dma16(ks + i * 1024 + lane * 16, kd + i * 1024 + lane * 16);
    }
    const char* vs = (const char*)vTb + ((size_t)(cchunk >> 5) + it2) * VTILE_B;
    char* vd = (char*)lds_v[b];
#pragma unroll
    for (int j = 0; j < 4; ++j) {
      int i = j * 4 + w;
      dma16(vs + i * 1024 + lane * 16, vd + i * 1024 + lane * 16);
    }
    if (w < 2) {
      int i = 16 + w;
      dma16(vs + i * 1024 + lane * 16, vd + i * 1024 + lane * 16);
    }
    if (w == 0 && lane < 32)
      dma16((const char*)meta + (size_t)(cchunk + it2 * 32) * 16 + lane * 16,
            (char*)lds_m[b] + lane * 16);
  };

  stage(0, 0);

  for (int it = 0; it < 32; ++it) {
    const int buf = it & 1;
    __syncthreads();                          // drains stage(it)
    if (it + 1 < 32) stage(it + 1, buf ^ 1);  // drains at NEXT barrier

    // QK^T with sigma-permuted candidate rows; 4 independent MFMA chains
    floatx4 at[2][2] = {};
#pragma unroll
    for (int t2 = 0; t2 < 2; ++t2) {
      const char* krow =
          (const char*)lds_k[buf] + ((((n & 12) << 1) + (n & 3) + 4 * t2) * 512);
#pragma unroll
      for (int s = 0; s < 8; s++) {
        half8 af = __builtin_bit_cast(half8, *(const uint4*)(krow + ((s * 64 + qd * 16) ^ sw16)));
        at[t2][0] = __builtin_amdgcn_mfma_f32_16x16x32_f16(af, gfr[0][s], at[t2][0], 0, 0, 0);
        at[t2][1] = __builtin_amdgcn_mfma_f32_16x16x32_f16(af, gfr[1][s], at[t2][1], 0, 0, 0);
      }
    }
    // mask/exp; pack directly into PV A-frag registers (c = qd*8 + 4*t2 + r)
    unsigned pk0[4], pk1[4];
#pragma unroll
    for (int t2 = 0; t2 < 2; ++t2) {
#pragma unroll
      for (int r = 0; r < 4; r++) {
        float4 mt = lds_m[buf][8 * qd + 4 * t2 + r];  // alpha, beta, xs, ys
        {
          float mn = fminf(fminf(mt.z - bxv[0].x, mt.w - bxv[0].y),
                           fminf(bxv[0].z - mt.z, bxv[0].w - mt.w));
          float targ = fmaf(mt.x, at[t2][0][r], mt.y) + gam[0];
          float e = (mn > 0.f) ? exp2f(fminf(targ, 0.f)) : 0.f;
          dsum0 += e;
          unsigned b = (unsigned)f2bf_bits(e);
          unsigned idx = t2 * 2 + (r >> 1);
          if ((r & 1) == 0) pk0[idx] = b;
          else pk0[idx] |= b << 16;
        }
        {
          float mn = fminf(fminf(mt.z - bxv[1].x, mt.w - bxv[1].y),
                           fminf(bxv[1].z - mt.z, bxv[1].w - mt.w));
          float targ = fmaf(mt.x, at[t2][1][r], mt.y) + gam[1];
          float e = (mn > 0.f) ? exp2f(fminf(targ, 0.f)) : 0.f;
          dsum1 += e;
          unsigned b = (unsigned)f2bf_bits(e);
          unsigned idx = t2 * 2 + (r >> 1);
          if ((r & 1) == 0) pk1[idx] = b;
          else pk1[idx] |= b << 16;
        }
      }
    }
    uint4 u0, u1;
    u0.x = pk0[0]; u0.y = pk0[1]; u0.z = pk0[2]; u0.w = pk0[3];
    u1.x = pk1[0]; u1.y = pk1[1]; u1.z = pk1[2]; u1.w = pk1[3];
    short8 a20 = __builtin_bit_cast(short8, u0);
    short8 a21 = __builtin_bit_cast(short8, u1);
#pragma unroll
    for (int dt = 0; dt < 16; ++dt) {
      const ushort_t* vr = &lds_v[buf][(dt * 16 + n) * VROW + qd * 8];
      short8 b2 = mk_s8(*(const uint2*)vr, *(const uint2*)(vr + 4));
      macc[0][dt] = __builtin_amdgcn_mfma_f32_16x16x32_bf16(a20, b2, macc[0][dt], 0, 0, 0);
      macc[1][dt] = __builtin_amdgcn_mfma_f32_16x16x32_bf16(a21, b2, macc[1][dt], 0, 0, 0);
    }
  }

  dsum0 += __shfl_xor(dsum0, 16, 64);
  dsum0 += __shfl_xor(dsum0, 32, 64);
  dsum1 += __shfl_xor(dsum1, 16, 64);
  dsum1 += __shfl_xor(dsum1, 32, 64);

  if (PART) {
    if (lane < 16) {
      den_out[(size_t)chunk * NPP + p0w + n] = dsum0;
      den_out[(size_t)chunk * NPP + p0w + 16 + n] = dsum1;
    }
    ushort_t* ab = (ushort_t*)acc_out + (size_t)chunk * NPP * DD;
#pragma unroll
    for (int pt = 0; pt < 2; ++pt)
#pragma unroll
      for (int dt = 0; dt < 16; ++dt)
#pragma unroll
        for (int r = 0; r < 4; r++)
          ab[(size_t)(p0w + pt * 16 + qd * 4 + r) * DD + dt * 16 + n] = f2bf_bits(macc[pt][dt][r]);
  } else {
    if (lane < 16) {
      atomicAdd(&den_out[p0w + n], dsum0);
      atomicAdd(&den_out[p0w + 16 + n], dsum1);
    }
    float* ab = (float*)acc_out;
#pragma unroll
    for (int pt = 0; pt < 2; ++pt)
#pragma unroll
      for (int dt = 0; dt < 16; ++dt)
#pragma unroll
        for (int r = 0; r < 4; r++)
          atomicAdd(&ab[(size_t)(p0w + pt * 16 + qd * 4 + r) * DD + dt * 16 + n],
                    macc[pt][dt][r]);
  }
}

// ---------------------------------------------------------------------------
// K4a: reduce bf16 partials over chunks + finalize (PART path)
// ---------------------------------------------------------------------------
__global__ __launch_bounds__(256) void reduce_finalize(const float* __restrict__ points_feat,
                                                       const ushort_t* __restrict__ acc_part,
                                                       const float* __restrict__ den_part,
                                                       float* __restrict__ out) {
  const int p = blockIdx.x, t = threadIdx.x;
  float s = 0.f;
#pragma unroll 4
  for (int c = 0; c < NCHUNK; ++c) s += bf2f(acc_part[((size_t)c * NPP + p) * DD + t]);
  float dn = den_part[(size_t)(t & 63) * NPP + p];
#pragma unroll
  for (int o = 1; o < 64; o <<= 1) dn += __shfl_xor(dn, o, 64);
  float m = (dn > 0.f) ? s / dn : 0.f;
  out[(size_t)p * DD + t] = points_feat[(size_t)p * DD + t] + m;
}

// K4b: atomic-path finalize
__global__ void finalize(const float* __restrict__ points_feat, const float* __restrict__ acc,
                         const float* __restrict__ den, float* __restrict__ out) {
  int p = blockIdx.x, d = threadIdx.x;
  float dn = den[p];
  float m = (dn > 0.f) ? acc[p * DD + d] / dn : 0.f;
  out[p * DD + d] = points_feat[p * DD + d] + m;
}

extern "C" void kernel_launch(void* const* d_in, const int* in_sizes, int n_in, void* d_out,
                              int out_size, void* d_ws, size_t ws_size, hipStream_t stream) {
  const float* points_feat = (const float*)d_in[0];
  const float* box_feat = (const float*)d_in[1];
  const float* centers = (const float*)d_in[2];
  const float* boxes = (const float*)d_in[3];
  const float* Wq = (const float*)d_in[4];
  const float* bq = (const float*)d_in[5];
  const float* Wk = (const float*)d_in[6];
  const float* bk = (const float*)d_in[7];
  const float* scales = (const float*)d_in[8];

  char* p = (char*)d_ws;
  ushort_t* ws_accP = (ushort_t*)p;  p += (size_t)NCHUNK * NPP * DD * 2;  // 33.55MB (bf16)
  float* ws_den = (float*)p;         p += (size_t)NCHUNK * NPP * 4;       // 0.26MB
  ushort_t* ws_bfR = (ushort_t*)p;   p += (size_t)NCC * DD * 2;           // 33.55MB
  ushort_t* ws_vTb = (ushort_t*)p;   p += (size_t)(NCC / 32) * VTILE_B;   // 37.75MB
  ushort_t* ws_Gt = (ushort_t*)p;    p += (size_t)NPP * DD * 2;           // 0.52MB
  float4* ws_meta = (float4*)p;      p += (size_t)NCC * 16;               // 1.05MB
  float* ws_gamma = (float*)p;       p += (size_t)NPP * 4;                // 4KB
  size_t need_part = (size_t)(p - (char*)d_ws);

  if (ws_size >= need_part) {
    // aux buffers (dead once attn starts) carved from the partials region
    ushort_t* ws_Mk = ws_accP;                         // 128KB
    float* ws_tu = (float*)(ws_Mk + (size_t)DD * DD);  // 1KB
    float* ws_tv = ws_tu + DD;                         // 1KB
    float* ws_s0 = ws_tv + DD;                         // 4B

    mk_prep<<<17, 256, 0, stream>>>(Wq, Wk, bq, bk, ws_Mk, ws_tu, ws_tv, ws_s0);
    btgt_prep<<<NCC / 32 + 16, 256, 0, stream>>>(box_feat, points_feat, centers, scales, ws_tu,
                                                 ws_tv, ws_s0, ws_Mk, ws_bfR, ws_vTb, ws_meta,
                                                 ws_Gt, ws_gamma);
    attn_kernel<true><<<dim3(NCHUNK, 8), 256, 0, stream>>>(ws_Gt, ws_gamma, ws_bfR, ws_vTb,
                                                           ws_meta, boxes, ws_accP, ws_den);
    reduce_finalize<<<NPP, 256, 0, stream>>>(points_feat, ws_accP, ws_den, (float*)d_out);
  } else {
    // compact fallback: fp32 atomic accumulation
    char* q = (char*)d_ws;
    ushort_t* f_bfR = (ushort_t*)q;  q += (size_t)NCC * DD * 2;
    ushort_t* f_vTb = (ushort_t*)q;  q += (size_t)(NCC / 32) * VTILE_B;
    ushort_t* f_Gt = (ushort_t*)q;   q += (size_t)NPP * DD * 2;
    float4* f_meta = (float4*)q;     q += (size_t)NCC * 16;
    float* f_gamma = (float*)q;      q += (size_t)NPP * 4;
    float* f_den = (float*)q;        q += (size_t)NPP * 4;
    float* f_acc = (float*)q;        q += (size_t)NPP * DD * 4;
    ushort_t* f_Mk = (ushort_t*)f_acc;  // carved: consumed before memset/attn
    float* f_tu = (float*)(f_Mk + (size_t)DD * DD);
    float* f_tv = f_tu + DD;
    float* f_s0 = f_tv + DD;

    mk_prep<<<17, 256, 0, stream>>>(Wq, Wk, bq, bk, f_Mk, f_tu, f_tv, f_s0);
    btgt_prep<<<NCC / 32 + 16, 256, 0, stream>>>(box_feat, points_feat, centers, scales, f_tu,
                                                 f_tv, f_s0, f_Mk, f_bfR, f_vTb, f_meta, f_Gt,
                                                 f_gamma);
    hipMemsetAsync(f_den, 0, ((size_t)NPP * DD + NPP) * sizeof(float), stream);
    attn_kernel<false><<<dim3(NCHUNK, 8), 256, 0, stream>>>(f_Gt, f_gamma, f_bfR, f_vTb, f_meta,
                                                            boxes, f_acc, f_den);
    finalize<<<NPP, DD, 0, stream>>>(points_feat, f_acc, f_den, (float*)d_out);
  }
}